// Round 1
// baseline (6404.665 us; speedup 1.0000x reference)
//
#include <hip/hip_runtime.h>

#define D_IN 8
#define D_MODEL 1024
#define DEPTH 12
#define D_INNER 2048
#define D_STATE 16
#define D_CONV 4
#define DT_RANK 64
#define BATCH 512

__device__ __forceinline__ float sigmoidf_(float x) { return 1.f / (1.f + expf(-x)); }
__device__ __forceinline__ float siluf_(float x) { return x * sigmoidf_(x); }
// match jax.nn.softplus = max(x,0) + log1p(exp(-|x|))
__device__ __forceinline__ float softplusf_(float x) { return fmaxf(x, 0.f) + log1pf(expf(-fabsf(x))); }

__device__ __forceinline__ float waveRedSum(float v) {
#pragma unroll
  for (int off = 32; off; off >>= 1) v += __shfl_xor(v, off);
  return v;
}

// h[b,m] = sum_k x_t[b,k] * Win[m,k] + bin[m]
__global__ __launch_bounds__(256) void k_input_proj(const float* __restrict__ xt,
    const float* __restrict__ Win, const float* __restrict__ bin, float* __restrict__ h) {
  int idx = blockIdx.x * 256 + threadIdx.x;
  int b = idx >> 10, m = idx & 1023;
  float acc = bin[m];
  const float* xr = xt + b * D_IN;
  const float* wr = Win + m * D_IN;
#pragma unroll
  for (int k = 0; k < D_IN; ++k) acc += xr[k] * wr[k];
  h[idx] = acc;
}

// C[M,N] = A[M,K] * W[N,K]^T   (fp32, LDS-tiled, BM=64, BN=NG*64, BK=16)
template <int NG>
__global__ __launch_bounds__(256) void k_gemm_nt(const float* __restrict__ A,
    const float* __restrict__ W, float* __restrict__ C, int M, int N, int K) {
  constexpr int BM = 64, BK = 16, BN = NG * 64;
  constexpr int LDA = BM + 4, LDB = BN + 4;
  __shared__ float As[BK][LDA];
  __shared__ float Ws[BK][LDB];
  const int t = threadIdx.x;
  const int m0 = blockIdx.y * BM, n0 = blockIdx.x * BN;
  const int lr = t >> 2, lk = (t & 3) << 2;   // loader: row, k-quad
  const int tm = t >> 4, tn = t & 15;         // compute: 16x16 thread grid
  float acc[4][NG * 4];
#pragma unroll
  for (int i = 0; i < 4; ++i)
#pragma unroll
    for (int j = 0; j < NG * 4; ++j) acc[i][j] = 0.f;

  for (int k0 = 0; k0 < K; k0 += BK) {
    float4 av = *(const float4*)&A[(size_t)(m0 + lr) * K + k0 + lk];
    As[lk + 0][lr] = av.x; As[lk + 1][lr] = av.y;
    As[lk + 2][lr] = av.z; As[lk + 3][lr] = av.w;
#pragma unroll
    for (int g = 0; g < NG; ++g) {
      float4 wv = *(const float4*)&W[(size_t)(n0 + g * 64 + lr) * K + k0 + lk];
      Ws[lk + 0][g * 64 + lr] = wv.x; Ws[lk + 1][g * 64 + lr] = wv.y;
      Ws[lk + 2][g * 64 + lr] = wv.z; Ws[lk + 3][g * 64 + lr] = wv.w;
    }
    __syncthreads();
#pragma unroll
    for (int kk = 0; kk < BK; ++kk) {
      float4 a = *(const float4*)&As[kk][tm * 4];
      float av4[4] = {a.x, a.y, a.z, a.w};
#pragma unroll
      for (int g = 0; g < NG; ++g) {
        float4 w = *(const float4*)&Ws[kk][g * 64 + tn * 4];
        float wv4[4] = {w.x, w.y, w.z, w.w};
#pragma unroll
        for (int i = 0; i < 4; ++i)
#pragma unroll
          for (int j = 0; j < 4; ++j) acc[i][g * 4 + j] += av4[i] * wv4[j];
      }
    }
    __syncthreads();
  }
#pragma unroll
  for (int i = 0; i < 4; ++i) {
    int m = m0 + tm * 4 + i;
#pragma unroll
    for (int g = 0; g < NG; ++g) {
      float4 r;
      r.x = acc[i][g * 4 + 0]; r.y = acc[i][g * 4 + 1];
      r.z = acc[i][g * 4 + 2]; r.w = acc[i][g * 4 + 3];
      *(float4*)&C[(size_t)m * N + n0 + g * 64 + tn * 4] = r;
    }
  }
}

// Fused per-batch-row: conv1d+SiLU -> x_proj -> dt_proj+softplus -> SSM -> gate
// 2 batch rows per block, 256 threads (4 waves).
__global__ __launch_bounds__(256) void k_fused(
    const float* __restrict__ xz,    // [512][4096]
    const float* __restrict__ cst,   // [512][2048][4]  (layer slice)
    const float* __restrict__ sst,   // [512][2048][16] (layer slice)
    const float* __restrict__ cw,    // [2048][4]
    const float* __restrict__ cb,    // [2048]
    const float* __restrict__ xpw,   // [96][2048]
    const float* __restrict__ dtw,   // [2048][64]
    const float* __restrict__ dtb,   // [2048]
    const float* __restrict__ alog,  // [2048][16]
    const float* __restrict__ dpar,  // [2048]
    float* __restrict__ y)           // [512][2048]
{
  __shared__ float sxc[2][D_INNER];
  __shared__ float sxdb[2][96];
  const int t = threadIdx.x;
  const int b0 = blockIdx.x * 2;

  // phase 1: conv + silu
#pragma unroll
  for (int bb = 0; bb < 2; ++bb) {
    const int b = b0 + bb;
    for (int d = t; d < D_INNER; d += 256) {
      float4 c = *(const float4*)&cst[((size_t)b * D_INNER + d) * 4];
      float4 w = *(const float4*)&cw[d * 4];
      float xv = xz[(size_t)b * 4096 + d];
      float a = c.y * w.x + c.z * w.y + c.w * w.z + xv * w.w + cb[d];
      sxc[bb][d] = siluf_(a);
    }
  }
  __syncthreads();

  // phase 2: x_proj (96 rows split over 4 waves, lane-split K + shfl reduce)
  const int wave = t >> 6, lane = t & 63;
  for (int r = wave * 24; r < wave * 24 + 24; ++r) {
    float a0 = 0.f, a1 = 0.f;
    const float* wr = &xpw[(size_t)r * D_INNER];
    for (int k = lane; k < D_INNER; k += 64) {
      float wv = wr[k];
      a0 += wv * sxc[0][k];
      a1 += wv * sxc[1][k];
    }
    a0 = waveRedSum(a0);
    a1 = waveRedSum(a1);
    if (lane == 0) { sxdb[0][r] = a0; sxdb[1][r] = a1; }
  }
  __syncthreads();

  // phase 3: dt_proj + softplus + SSM + gate
  for (int d = t; d < D_INNER; d += 256) {
    float An[D_STATE];
#pragma unroll
    for (int n = 0; n < D_STATE; ++n) An[n] = -expf(alog[d * D_STATE + n]);
    float dtwv[DT_RANK];
#pragma unroll
    for (int j4 = 0; j4 < DT_RANK / 4; ++j4)
      *(float4*)&dtwv[j4 * 4] = *(const float4*)&dtw[(size_t)d * DT_RANK + j4 * 4];
    const float dtbv = dtb[d], dp = dpar[d];
#pragma unroll
    for (int bb = 0; bb < 2; ++bb) {
      const int b = b0 + bb;
      float dtr = dtbv;
#pragma unroll
      for (int j = 0; j < DT_RANK; ++j) dtr += sxdb[bb][j] * dtwv[j];
      float dtv = softplusf_(dtr);
      float xcv = sxc[bb][d];
      float dx = dtv * xcv;
      const float* srow = &sst[((size_t)b * D_INNER + d) * D_STATE];
      float acc = 0.f;
#pragma unroll
      for (int n = 0; n < D_STATE; ++n) {
        float Bn = sxdb[bb][DT_RANK + n];
        float Cn = sxdb[bb][DT_RANK + D_STATE + n];
        float sNew = srow[n] * expf(dtv * An[n]) + dx * Bn;
        acc += sNew * Cn;
      }
      float yv = acc + dp * xcv;
      float zv = xz[(size_t)b * 4096 + D_INNER + d];
      yv *= siluf_(zv);
      y[(size_t)b * D_INNER + d] = yv;
    }
  }
}

__global__ __launch_bounds__(256) void k_layernorm(const float* __restrict__ h,
    const float* __restrict__ lnw, const float* __restrict__ lnb, float* __restrict__ out) {
  __shared__ float red[4];
  const int b = blockIdx.x, t = threadIdx.x;
  const float* row = h + (size_t)b * D_MODEL;
  float4 x = *(const float4*)&row[t * 4];
  float s = x.x + x.y + x.z + x.w;
  s = waveRedSum(s);
  const int wave = t >> 6, lane = t & 63;
  if (lane == 0) red[wave] = s;
  __syncthreads();
  float mu = (red[0] + red[1] + red[2] + red[3]) * (1.f / 1024.f);
  float d0 = x.x - mu, d1 = x.y - mu, d2 = x.z - mu, d3 = x.w - mu;
  float q = d0 * d0 + d1 * d1 + d2 * d2 + d3 * d3;
  q = waveRedSum(q);
  __syncthreads();
  if (lane == 0) red[wave] = q;
  __syncthreads();
  float var = (red[0] + red[1] + red[2] + red[3]) * (1.f / 1024.f);
  float inv = 1.f / sqrtf(var + 1e-5f);
  float4 wv = *(const float4*)&lnw[t * 4];
  float4 bv = *(const float4*)&lnb[t * 4];
  float4 o;
  o.x = d0 * inv * wv.x + bv.x;
  o.y = d1 * inv * wv.y + bv.y;
  o.z = d2 * inv * wv.z + bv.z;
  o.w = d3 * inv * wv.w + bv.w;
  *(float4*)&out[(size_t)b * D_MODEL + t * 4] = o;
}

extern "C" void kernel_launch(void* const* d_in, const int* in_sizes, int n_in,
                              void* d_out, int out_size, void* d_ws, size_t ws_size,
                              hipStream_t stream) {
  const float* x_t  = (const float*)d_in[0];
  const float* cst  = (const float*)d_in[1];
  const float* sst  = (const float*)d_in[2];
  const float* Win  = (const float*)d_in[3];
  const float* bin  = (const float*)d_in[4];
  const float* ipw  = (const float*)d_in[5];
  const float* cw   = (const float*)d_in[6];
  const float* cb   = (const float*)d_in[7];
  const float* xpw  = (const float*)d_in[8];
  const float* dtw  = (const float*)d_in[9];
  const float* dtb  = (const float*)d_in[10];
  const float* alog = (const float*)d_in[11];
  const float* dpar = (const float*)d_in[12];
  const float* opw  = (const float*)d_in[13];
  const float* lnw  = (const float*)d_in[14];
  const float* lnb  = (const float*)d_in[15];

  float* ws = (float*)d_ws;
  float* h  = ws;                      // 512*1024
  float* xz = ws + 524288;             // 512*4096
  float* y  = xz + 2097152;            // 512*2048

  k_input_proj<<<2048, 256, 0, stream>>>(x_t, Win, bin, h);

  for (int l = 0; l < DEPTH; ++l) {
    k_gemm_nt<2><<<dim3(4096 / 128, 512 / 64), 256, 0, stream>>>(
        h, ipw + (size_t)l * 4096 * 1024, xz, 512, 4096, 1024);
    k_fused<<<256, 256, 0, stream>>>(
        xz,
        cst + (size_t)l * BATCH * D_INNER * D_CONV,
        sst + (size_t)l * BATCH * D_INNER * D_STATE,
        cw + (size_t)l * D_INNER * D_CONV, cb + (size_t)l * D_INNER,
        xpw + (size_t)l * 96 * D_INNER,
        dtw + (size_t)l * D_INNER * DT_RANK, dtb + (size_t)l * D_INNER,
        alog + (size_t)l * D_INNER * D_STATE, dpar + (size_t)l * D_INNER,
        y);
    k_gemm_nt<1><<<dim3(1024 / 64, 512 / 64), 256, 0, stream>>>(
        y, opw + (size_t)l * 1024 * 2048, h, 512, 1024, 2048);
  }

  k_layernorm<<<512, 256, 0, stream>>>(h, lnw, lnb, (float*)d_out);
}

// Round 2
// 4865.400 us; speedup vs baseline: 1.3164x; 1.3164x over previous
//
#include <hip/hip_runtime.h>

#define D_IN 8
#define D_MODEL 1024
#define DEPTH 12
#define D_INNER 2048
#define D_STATE 16
#define D_CONV 4
#define DT_RANK 64
#define BATCH 512

typedef unsigned short ushort_t;
typedef unsigned int uint_t;
typedef __attribute__((ext_vector_type(8))) short short8;
typedef __attribute__((ext_vector_type(16))) float f32x16;

__device__ __forceinline__ float sigmoidf_(float x) { return 1.f / (1.f + expf(-x)); }
__device__ __forceinline__ float siluf_(float x) { return x * sigmoidf_(x); }
__device__ __forceinline__ float softplusf_(float x) { return fmaxf(x, 0.f) + log1pf(expf(-fabsf(x))); }

__device__ __forceinline__ float waveRedSum(float v) {
#pragma unroll
  for (int off = 32; off; off >>= 1) v += __shfl_xor(v, off);
  return v;
}

// ---- bf16 3-way split helpers (RNE) ----
__device__ __forceinline__ ushort_t f2bf(float x) {
  uint_t u = __float_as_uint(x);
  u += 0x7fffu + ((u >> 16) & 1u);
  return (ushort_t)(u >> 16);
}
__device__ __forceinline__ float bf2f(ushort_t h) { return __uint_as_float((uint_t)h << 16); }
__device__ __forceinline__ void split3(float x, ushort_t& s0, ushort_t& s1, ushort_t& s2) {
  s0 = f2bf(x); float r = x - bf2f(s0);
  s1 = f2bf(r); r -= bf2f(s1);
  s2 = f2bf(r);
}
__device__ __forceinline__ uint4 pack8(const ushort_t* u) {
  uint4 v;
  v.x = (uint_t)u[0] | ((uint_t)u[1] << 16);
  v.y = (uint_t)u[2] | ((uint_t)u[3] << 16);
  v.z = (uint_t)u[4] | ((uint_t)u[5] << 16);
  v.w = (uint_t)u[6] | ((uint_t)u[7] << 16);
  return v;
}

// swizzled LDS offset (ushort units): rows of 64 bf16 = 128B, 16B slot XOR-spread
__device__ __forceinline__ int lds_off(int row, int kb) {
  return row * 64 + ((kb ^ ((row & 7) << 4)) >> 1);
}

// h[b,m] = x_t[b,:] . Win[m,:] + bin[m]  -> bf16 3-split
__global__ __launch_bounds__(256) void k_input_proj(const float* __restrict__ xt,
    const float* __restrict__ Win, const float* __restrict__ bin,
    ushort_t* __restrict__ h0, ushort_t* __restrict__ h1, ushort_t* __restrict__ h2) {
  int idx = blockIdx.x * 256 + threadIdx.x;
  int b = idx >> 10, m = idx & 1023;
  float acc = bin[m];
  const float* xr = xt + b * D_IN;
  const float* wr = Win + m * D_IN;
#pragma unroll
  for (int k = 0; k < D_IN; ++k) acc += xr[k] * wr[k];
  ushort_t s0, s1, s2; split3(acc, s0, s1, s2);
  h0[idx] = s0; h1[idx] = s1; h2[idx] = s2;
}

// C[M,N] = A.W^T via bf16x3 / 6-product MFMA 32x32x16.
// A: 3 pre-split bf16 arrays [M][K]. W: fp32 [N][K] (converted during staging).
// Block: BM x 64, 256 thr = 4 waves; wave tile 32m x 64n; NWK-way intra-block split-K.
template <int BM, int NWK, bool SPLITOUT>
__global__ __launch_bounds__(256) void k_gemm3(
    const ushort_t* __restrict__ a0, const ushort_t* __restrict__ a1, const ushort_t* __restrict__ a2,
    const float* __restrict__ W, float* __restrict__ C,
    ushort_t* __restrict__ c0, ushort_t* __restrict__ c1, ushort_t* __restrict__ c2,
    int N, int K, int MBLK) {
  constexpr int A_SZ = BM * 64;   // ushorts per split
  constexpr int B_SZ = 64 * 64;
  __shared__ ushort_t lds[3 * A_SZ + 3 * B_SZ];
  ushort_t* Asl = lds;
  ushort_t* Bsl = lds + 3 * A_SZ;

  const int t = threadIdx.x;
  const int lane = t & 63, wave = t >> 6;
  const int ks = wave & (NWK - 1);
  const int wm = wave / NWK;

  // XCD-chunked bijective swizzle (grid % 8 == 0), m-fastest within chunk
  const int cpx = gridDim.x >> 3;
  const int id = blockIdx.x;
  const int swz = (id & 7) * cpx + (id >> 3);
  const int mb = swz % MBLK, nb = swz / MBLK;
  const int m0 = mb * BM, n0 = nb * 64;

  f32x16 acc[2];
#pragma unroll
  for (int i = 0; i < 16; ++i) { acc[0][i] = 0.f; acc[1][i] = 0.f; }

  constexpr int CPW = 4 / NWK;  // k16 chunks per wave per BK=64 step

  for (int k0 = 0; k0 < K; k0 += 64) {
    __syncthreads();
    // ---- stage A (pre-split bf16) ----
    if (BM == 64) {
      int r = t >> 2, sl = (t & 3) * 2;
#pragma unroll
      for (int s = 0; s < 3; ++s) {
        const ushort_t* g = (s == 0 ? a0 : s == 1 ? a1 : a2) + (size_t)(m0 + r) * K + k0 + sl * 8;
        *(uint4*)&Asl[s * A_SZ + lds_off(r, sl * 16)]      = *(const uint4*)g;
        *(uint4*)&Asl[s * A_SZ + lds_off(r, sl * 16 + 16)] = *(const uint4*)(g + 8);
      }
    } else {
      int r = t >> 3, sl = t & 7;
#pragma unroll
      for (int s = 0; s < 3; ++s) {
        const ushort_t* g = (s == 0 ? a0 : s == 1 ? a1 : a2) + (size_t)(m0 + r) * K + k0 + sl * 8;
        *(uint4*)&Asl[s * A_SZ + lds_off(r, sl * 16)] = *(const uint4*)g;
      }
    }
    // ---- stage B: load fp32 W, split to 3x bf16 ----
    {
      int r = t >> 2, cf = (t & 3) * 16;
      const float* g = W + (size_t)(n0 + r) * K + k0 + cf;
      float fv[16];
      *(float4*)&fv[0]  = *(const float4*)(g + 0);
      *(float4*)&fv[4]  = *(const float4*)(g + 4);
      *(float4*)&fv[8]  = *(const float4*)(g + 8);
      *(float4*)&fv[12] = *(const float4*)(g + 12);
      ushort_t u0[16], u1[16], u2[16];
#pragma unroll
      for (int i = 0; i < 16; ++i) split3(fv[i], u0[i], u1[i], u2[i]);
      int kb0 = cf * 2;
      *(uint4*)&Bsl[0 * B_SZ + lds_off(r, kb0)]      = pack8(u0);
      *(uint4*)&Bsl[0 * B_SZ + lds_off(r, kb0 + 16)] = pack8(u0 + 8);
      *(uint4*)&Bsl[1 * B_SZ + lds_off(r, kb0)]      = pack8(u1);
      *(uint4*)&Bsl[1 * B_SZ + lds_off(r, kb0 + 16)] = pack8(u1 + 8);
      *(uint4*)&Bsl[2 * B_SZ + lds_off(r, kb0)]      = pack8(u2);
      *(uint4*)&Bsl[2 * B_SZ + lds_off(r, kb0 + 16)] = pack8(u2 + 8);
    }
    __syncthreads();
    // ---- compute ----
#pragma unroll
    for (int cc = 0; cc < CPW; ++cc) {
      const int kc = ks * CPW + cc;
      const int kb = kc * 32 + (lane >> 5) * 16;
      const int ra = wm * 32 + (lane & 31);
      short8 af[3], bfr[2][3];
#pragma unroll
      for (int s = 0; s < 3; ++s)
        af[s] = *(const short8*)&Asl[s * A_SZ + lds_off(ra, kb)];
#pragma unroll
      for (int nf = 0; nf < 2; ++nf) {
        const int rb = nf * 32 + (lane & 31);
#pragma unroll
        for (int s = 0; s < 3; ++s)
          bfr[nf][s] = *(const short8*)&Bsl[s * B_SZ + lds_off(rb, kb)];
      }
#pragma unroll
      for (int nf = 0; nf < 2; ++nf) {
        acc[nf] = __builtin_amdgcn_mfma_f32_32x32x16_bf16(af[0], bfr[nf][0], acc[nf], 0, 0, 0);
        acc[nf] = __builtin_amdgcn_mfma_f32_32x32x16_bf16(af[0], bfr[nf][1], acc[nf], 0, 0, 0);
        acc[nf] = __builtin_amdgcn_mfma_f32_32x32x16_bf16(af[1], bfr[nf][0], acc[nf], 0, 0, 0);
        acc[nf] = __builtin_amdgcn_mfma_f32_32x32x16_bf16(af[1], bfr[nf][1], acc[nf], 0, 0, 0);
        acc[nf] = __builtin_amdgcn_mfma_f32_32x32x16_bf16(af[2], bfr[nf][0], acc[nf], 0, 0, 0);
        acc[nf] = __builtin_amdgcn_mfma_f32_32x32x16_bf16(af[0], bfr[nf][2], acc[nf], 0, 0, 0);
      }
    }
  }

  // ---- intra-block split-K reduce via LDS, then write ----
  __syncthreads();
  float* red = (float*)lds;
  if (ks != 0) {
    const int reg = (wm * (NWK - 1) + (ks - 1)) * 2112;
#pragma unroll
    for (int nf = 0; nf < 2; ++nf)
#pragma unroll
      for (int r = 0; r < 16; ++r)
        red[reg + lane * 33 + nf * 16 + r] = acc[nf][r];
  }
  __syncthreads();
  if (ks == 0) {
#pragma unroll
    for (int p = 0; p < NWK - 1; ++p) {
      const int reg = (wm * (NWK - 1) + p) * 2112;
#pragma unroll
      for (int nf = 0; nf < 2; ++nf)
#pragma unroll
        for (int r = 0; r < 16; ++r)
          acc[nf][r] += red[reg + lane * 33 + nf * 16 + r];
    }
#pragma unroll
    for (int nf = 0; nf < 2; ++nf) {
      const int n = n0 + nf * 32 + (lane & 31);
#pragma unroll
      for (int r = 0; r < 16; ++r) {
        const int m = m0 + wm * 32 + (r & 3) + 8 * (r >> 2) + 4 * (lane >> 5);
        const float v = acc[nf][r];
        const size_t off = (size_t)m * N + n;
        C[off] = v;
        if constexpr (SPLITOUT) {
          ushort_t s0, s1, s2; split3(v, s0, s1, s2);
          c0[off] = s0; c1[off] = s1; c2[off] = s2;
        }
      }
    }
  }
}

// Fused: conv1d+SiLU -> x_proj -> dt_proj+softplus -> SSM -> gate. Writes y as bf16 3-split.
__global__ __launch_bounds__(256) void k_fused(
    const float* __restrict__ xz, const float* __restrict__ cst, const float* __restrict__ sst,
    const float* __restrict__ cw, const float* __restrict__ cb,
    const float* __restrict__ xpw, const float* __restrict__ dtw, const float* __restrict__ dtb,
    const float* __restrict__ alog, const float* __restrict__ dpar,
    ushort_t* __restrict__ y0, ushort_t* __restrict__ y1, ushort_t* __restrict__ y2) {
  __shared__ float sxc[2][D_INNER];
  __shared__ float sxdb[2][96];
  const int t = threadIdx.x;
  const int b0 = blockIdx.x * 2;

#pragma unroll
  for (int bb = 0; bb < 2; ++bb) {
    const int b = b0 + bb;
    for (int d = t; d < D_INNER; d += 256) {
      float4 c = *(const float4*)&cst[((size_t)b * D_INNER + d) * 4];
      float4 w = *(const float4*)&cw[d * 4];
      float xv = xz[(size_t)b * 4096 + d];
      float a = c.y * w.x + c.z * w.y + c.w * w.z + xv * w.w + cb[d];
      sxc[bb][d] = siluf_(a);
    }
  }
  __syncthreads();

  const int wave = t >> 6, lane = t & 63;
  for (int r = wave * 24; r < wave * 24 + 24; ++r) {
    float a0 = 0.f, a1 = 0.f;
    const float* wr = &xpw[(size_t)r * D_INNER];
    for (int k = lane; k < D_INNER; k += 64) {
      float wv = wr[k];
      a0 += wv * sxc[0][k];
      a1 += wv * sxc[1][k];
    }
    a0 = waveRedSum(a0);
    a1 = waveRedSum(a1);
    if (lane == 0) { sxdb[0][r] = a0; sxdb[1][r] = a1; }
  }
  __syncthreads();

  for (int d = t; d < D_INNER; d += 256) {
    float An[D_STATE];
#pragma unroll
    for (int n = 0; n < D_STATE; ++n) An[n] = -expf(alog[d * D_STATE + n]);
    float dtwv[DT_RANK];
#pragma unroll
    for (int j4 = 0; j4 < DT_RANK / 4; ++j4)
      *(float4*)&dtwv[j4 * 4] = *(const float4*)&dtw[(size_t)d * DT_RANK + j4 * 4];
    const float dtbv = dtb[d], dp = dpar[d];
#pragma unroll
    for (int bb = 0; bb < 2; ++bb) {
      const int b = b0 + bb;
      float dtr = dtbv;
#pragma unroll
      for (int j = 0; j < DT_RANK; ++j) dtr += sxdb[bb][j] * dtwv[j];
      float dtv = softplusf_(dtr);
      float xcv = sxc[bb][d];
      float dx = dtv * xcv;
      const float* srow = &sst[((size_t)b * D_INNER + d) * D_STATE];
      float acc = 0.f;
#pragma unroll
      for (int n = 0; n < D_STATE; ++n) {
        float Bn = sxdb[bb][DT_RANK + n];
        float Cn = sxdb[bb][DT_RANK + D_STATE + n];
        float sNew = srow[n] * expf(dtv * An[n]) + dx * Bn;
        acc += sNew * Cn;
      }
      float yv = acc + dp * xcv;
      float zv = xz[(size_t)b * 4096 + D_INNER + d];
      yv *= siluf_(zv);
      ushort_t s0, s1, s2; split3(yv, s0, s1, s2);
      const size_t off = (size_t)b * D_INNER + d;
      y0[off] = s0; y1[off] = s1; y2[off] = s2;
    }
  }
}

__global__ __launch_bounds__(256) void k_layernorm(const float* __restrict__ h,
    const float* __restrict__ lnw, const float* __restrict__ lnb, float* __restrict__ out) {
  __shared__ float red[4];
  const int b = blockIdx.x, t = threadIdx.x;
  const float* row = h + (size_t)b * D_MODEL;
  float4 x = *(const float4*)&row[t * 4];
  float s = x.x + x.y + x.z + x.w;
  s = waveRedSum(s);
  const int wave = t >> 6, lane = t & 63;
  if (lane == 0) red[wave] = s;
  __syncthreads();
  float mu = (red[0] + red[1] + red[2] + red[3]) * (1.f / 1024.f);
  float d0 = x.x - mu, d1 = x.y - mu, d2 = x.z - mu, d3 = x.w - mu;
  float q = d0 * d0 + d1 * d1 + d2 * d2 + d3 * d3;
  q = waveRedSum(q);
  __syncthreads();
  if (lane == 0) red[wave] = q;
  __syncthreads();
  float var = (red[0] + red[1] + red[2] + red[3]) * (1.f / 1024.f);
  float inv = 1.f / sqrtf(var + 1e-5f);
  float4 wv = *(const float4*)&lnw[t * 4];
  float4 bv = *(const float4*)&lnb[t * 4];
  float4 o;
  o.x = d0 * inv * wv.x + bv.x;
  o.y = d1 * inv * wv.y + bv.y;
  o.z = d2 * inv * wv.z + bv.z;
  o.w = d3 * inv * wv.w + bv.w;
  *(float4*)&out[(size_t)b * D_MODEL + t * 4] = o;
}

extern "C" void kernel_launch(void* const* d_in, const int* in_sizes, int n_in,
                              void* d_out, int out_size, void* d_ws, size_t ws_size,
                              hipStream_t stream) {
  const float* x_t  = (const float*)d_in[0];
  const float* cst  = (const float*)d_in[1];
  const float* sst  = (const float*)d_in[2];
  const float* Win  = (const float*)d_in[3];
  const float* bin  = (const float*)d_in[4];
  const float* ipw  = (const float*)d_in[5];
  const float* cw   = (const float*)d_in[6];
  const float* cb   = (const float*)d_in[7];
  const float* xpw  = (const float*)d_in[8];
  const float* dtw  = (const float*)d_in[9];
  const float* dtb  = (const float*)d_in[10];
  const float* alog = (const float*)d_in[11];
  const float* dpar = (const float*)d_in[12];
  const float* opw  = (const float*)d_in[13];
  const float* lnw  = (const float*)d_in[14];
  const float* lnb  = (const float*)d_in[15];

  float* ws = (float*)d_ws;
  float* xz = ws;                              // 512*4096 f32
  float* h  = ws + 2097152;                    // 512*1024 f32
  ushort_t* u  = (ushort_t*)(ws + 2097152 + 524288);
  ushort_t* h0 = u;
  ushort_t* h1 = h0 + 524288;
  ushort_t* h2 = h1 + 524288;
  ushort_t* y0 = h2 + 524288;                  // 512*2048 each
  ushort_t* y1 = y0 + 1048576;
  ushort_t* y2 = y1 + 1048576;

  k_input_proj<<<2048, 256, 0, stream>>>(x_t, Win, bin, h0, h1, h2);

  for (int l = 0; l < DEPTH; ++l) {
    // in_proj: [512,4096] = h[512,1024] . ipw^T
    k_gemm3<64, 2, false><<<(512 / 64) * (4096 / 64), 256, 0, stream>>>(
        h0, h1, h2, ipw + (size_t)l * 4096 * 1024, xz,
        nullptr, nullptr, nullptr, 4096, 1024, 512 / 64);
    k_fused<<<256, 256, 0, stream>>>(
        xz,
        cst + (size_t)l * BATCH * D_INNER * D_CONV,
        sst + (size_t)l * BATCH * D_INNER * D_STATE,
        cw + (size_t)l * D_INNER * D_CONV, cb + (size_t)l * D_INNER,
        xpw + (size_t)l * 96 * D_INNER,
        dtw + (size_t)l * D_INNER * DT_RANK, dtb + (size_t)l * D_INNER,
        alog + (size_t)l * D_INNER * D_STATE, dpar + (size_t)l * D_INNER,
        y0, y1, y2);
    // out_proj: h[512,1024] = y[512,2048] . opw^T ; also emit h splits for next layer
    k_gemm3<32, 4, true><<<(512 / 32) * (1024 / 64), 256, 0, stream>>>(
        y0, y1, y2, opw + (size_t)l * 1024 * 2048, h,
        h0, h1, h2, 1024, 2048, 512 / 32);
  }

  k_layernorm<<<512, 256, 0, stream>>>(h, lnw, lnb, (float*)d_out);
}

// Round 3
// 4746.268 us; speedup vs baseline: 1.3494x; 1.0251x over previous
//
#include <hip/hip_runtime.h>

#define D_IN 8
#define D_MODEL 1024
#define DEPTH 12
#define D_INNER 2048
#define D_STATE 16
#define D_CONV 4
#define DT_RANK 64
#define BATCH 512

typedef unsigned short ushort_t;
typedef unsigned int uint_t;
typedef __attribute__((ext_vector_type(8))) short short8;
typedef __attribute__((ext_vector_type(16))) float f32x16;

__device__ __forceinline__ float sigmoidf_(float x) { return 1.f / (1.f + expf(-x)); }
__device__ __forceinline__ float siluf_(float x) { return x * sigmoidf_(x); }
__device__ __forceinline__ float softplusf_(float x) { return fmaxf(x, 0.f) + log1pf(expf(-fabsf(x))); }

__device__ __forceinline__ float waveRedSum(float v) {
#pragma unroll
  for (int off = 32; off; off >>= 1) v += __shfl_xor(v, off);
  return v;
}

// ---- bf16 3-way split helpers (RNE) ----
__device__ __forceinline__ ushort_t f2bf(float x) {
  uint_t u = __float_as_uint(x);
  u += 0x7fffu + ((u >> 16) & 1u);
  return (ushort_t)(u >> 16);
}
__device__ __forceinline__ float bf2f(ushort_t h) { return __uint_as_float((uint_t)h << 16); }
__device__ __forceinline__ void split3(float x, ushort_t& s0, ushort_t& s1, ushort_t& s2) {
  s0 = f2bf(x); float r = x - bf2f(s0);
  s1 = f2bf(r); r -= bf2f(s1);
  s2 = f2bf(r);
}
__device__ __forceinline__ uint4 pack8(const ushort_t* u) {
  uint4 v;
  v.x = (uint_t)u[0] | ((uint_t)u[1] << 16);
  v.y = (uint_t)u[2] | ((uint_t)u[3] << 16);
  v.z = (uint_t)u[4] | ((uint_t)u[5] << 16);
  v.w = (uint_t)u[6] | ((uint_t)u[7] << 16);
  return v;
}

// swizzled LDS offset (ushort units). Row = 64 bf16 = 128B; kb = BYTE offset in row.
// XOR spreads 16B slots by (row&7) -> conflict-free b128 column reads.
__device__ __forceinline__ int lds_off(int row, int kb) {
  return row * 64 + ((kb ^ ((row & 7) << 4)) >> 1);
}

// ---- weight pre-split: fp32 plane -> 3 bf16 planes ----
__global__ __launch_bounds__(256) void k_presplit(const float* __restrict__ W,
    ushort_t* __restrict__ p0, ushort_t* __restrict__ p1, ushort_t* __restrict__ p2, int n8) {
  for (int i = blockIdx.x * 256 + threadIdx.x; i < n8; i += gridDim.x * 256) {
    const float* g = W + (size_t)i * 8;
    float fv[8];
    *(float4*)&fv[0] = *(const float4*)(g + 0);
    *(float4*)&fv[4] = *(const float4*)(g + 4);
    ushort_t u0[8], u1[8], u2[8];
#pragma unroll
    for (int j = 0; j < 8; ++j) split3(fv[j], u0[j], u1[j], u2[j]);
    ((uint4*)p0)[i] = pack8(u0);
    ((uint4*)p1)[i] = pack8(u1);
    ((uint4*)p2)[i] = pack8(u2);
  }
}

// h[b,m] = x_t[b,:] . Win[m,:] + bin[m]  -> bf16 3-split
__global__ __launch_bounds__(256) void k_input_proj(const float* __restrict__ xt,
    const float* __restrict__ Win, const float* __restrict__ bin,
    ushort_t* __restrict__ h0, ushort_t* __restrict__ h1, ushort_t* __restrict__ h2) {
  int idx = blockIdx.x * 256 + threadIdx.x;
  int b = idx >> 10, m = idx & 1023;
  float acc = bin[m];
  const float* xr = xt + b * D_IN;
  const float* wr = Win + m * D_IN;
#pragma unroll
  for (int k = 0; k < D_IN; ++k) acc += xr[k] * wr[k];
  ushort_t s0, s1, s2; split3(acc, s0, s1, s2);
  h0[idx] = s0; h1[idx] = s1; h2[idx] = s2;
}

// C_partial[kb] = A . B^T over k-slice. A,B pre-split bf16 planes [rows][K].
// Block tile 64m x 128n. 4 waves = 2 n-groups x 2 k-slices. Wave tile 64m x 64n
// (P=2 m-frags, Q=2 n-frags) -> 12 ds_read_b128 per 24 MFMA per k16-chunk.
template <int MBLK, int NBLK, int KSPLIT, int KLEN>
__global__ __launch_bounds__(256, 2) void k_gemm6(
    const ushort_t* __restrict__ a0, const ushort_t* __restrict__ a1, const ushort_t* __restrict__ a2,
    const ushort_t* __restrict__ b0, const ushort_t* __restrict__ b1, const ushort_t* __restrict__ b2,
    float* __restrict__ P, int N, int K) {
  constexpr int A_SZ = 64 * 64, B_SZ = 128 * 64;
  __shared__ ushort_t lds[3 * A_SZ + 3 * B_SZ];  // 73728 B
  ushort_t* Asl = lds;
  ushort_t* Bsl = lds + 3 * A_SZ;

  const int t = threadIdx.x, lane = t & 63, w = t >> 6;
  const int wm = w >> 1;   // n-group (0,1)
  const int ks = w & 1;    // k-slice (0,1)

  // XCD-chunked bijective swizzle (grid = MBLK*NBLK*KSPLIT, multiple of 8)
  constexpr int GRID = MBLK * NBLK * KSPLIT;
  const int id = blockIdx.x;
  const int swz = (id & 7) * (GRID >> 3) + (id >> 3);
  const int kb = swz / (MBLK * NBLK);
  const int r2 = swz % (MBLK * NBLK);
  const int m0 = (r2 % MBLK) * 64, n0 = (r2 / MBLK) * 128;
  const size_t kbase0 = (size_t)kb * KLEN;

  f32x16 acc[2][2];
#pragma unroll
  for (int i = 0; i < 2; ++i)
#pragma unroll
    for (int j = 0; j < 2; ++j)
#pragma unroll
      for (int r = 0; r < 16; ++r) acc[i][j][r] = 0.f;

  const int rA = t >> 2, slA = (t & 3) * 2;  // A: 64 rows x 8 slots, 2 slots/thread
  const int rB = t >> 1, slB = (t & 1) * 4;  // B: 128 rows x 8 slots, 4 slots/thread
  const ushort_t* APL[3] = {a0, a1, a2};
  const ushort_t* BPL[3] = {b0, b1, b2};

  for (int step = 0; step < KLEN / 64; ++step) {
    const size_t kofs = kbase0 + step * 64;
    __syncthreads();
#pragma unroll
    for (int s = 0; s < 3; ++s) {
      const ushort_t* ga = APL[s] + (size_t)(m0 + rA) * K + kofs + slA * 8;
      uint4 v0 = *(const uint4*)ga;
      uint4 v1 = *(const uint4*)(ga + 8);
      *(uint4*)&Asl[s * A_SZ + lds_off(rA, slA * 16)]      = v0;
      *(uint4*)&Asl[s * A_SZ + lds_off(rA, slA * 16 + 16)] = v1;
    }
#pragma unroll
    for (int s = 0; s < 3; ++s) {
      const ushort_t* gb = BPL[s] + (size_t)(n0 + rB) * K + kofs + slB * 8;
      uint4 u0 = *(const uint4*)(gb + 0);
      uint4 u1 = *(const uint4*)(gb + 8);
      uint4 u2 = *(const uint4*)(gb + 16);
      uint4 u3 = *(const uint4*)(gb + 24);
      *(uint4*)&Bsl[s * B_SZ + lds_off(rB, (slB + 0) * 16)] = u0;
      *(uint4*)&Bsl[s * B_SZ + lds_off(rB, (slB + 1) * 16)] = u1;
      *(uint4*)&Bsl[s * B_SZ + lds_off(rB, (slB + 2) * 16)] = u2;
      *(uint4*)&Bsl[s * B_SZ + lds_off(rB, (slB + 3) * 16)] = u3;
    }
    __syncthreads();
#pragma unroll
    for (int cc = 0; cc < 2; ++cc) {
      const int kc = ks * 2 + cc;                  // k16-chunk in [0,4)
      const int kbyte = kc * 32 + (lane >> 5) * 16;
      short8 af[2][3], bf[2][3];
#pragma unroll
      for (int mf = 0; mf < 2; ++mf)
#pragma unroll
        for (int s = 0; s < 3; ++s)
          af[mf][s] = *(const short8*)&Asl[s * A_SZ + lds_off(mf * 32 + (lane & 31), kbyte)];
#pragma unroll
      for (int nf = 0; nf < 2; ++nf)
#pragma unroll
        for (int s = 0; s < 3; ++s)
          bf[nf][s] = *(const short8*)&Bsl[s * B_SZ + lds_off(wm * 64 + nf * 32 + (lane & 31), kbyte)];
#pragma unroll
      for (int mf = 0; mf < 2; ++mf)
#pragma unroll
        for (int nf = 0; nf < 2; ++nf) {
          acc[mf][nf] = __builtin_amdgcn_mfma_f32_32x32x16_bf16(af[mf][0], bf[nf][0], acc[mf][nf], 0, 0, 0);
          acc[mf][nf] = __builtin_amdgcn_mfma_f32_32x32x16_bf16(af[mf][0], bf[nf][1], acc[mf][nf], 0, 0, 0);
          acc[mf][nf] = __builtin_amdgcn_mfma_f32_32x32x16_bf16(af[mf][1], bf[nf][0], acc[mf][nf], 0, 0, 0);
          acc[mf][nf] = __builtin_amdgcn_mfma_f32_32x32x16_bf16(af[mf][1], bf[nf][1], acc[mf][nf], 0, 0, 0);
          acc[mf][nf] = __builtin_amdgcn_mfma_f32_32x32x16_bf16(af[mf][2], bf[nf][0], acc[mf][nf], 0, 0, 0);
          acc[mf][nf] = __builtin_amdgcn_mfma_f32_32x32x16_bf16(af[mf][0], bf[nf][2], acc[mf][nf], 0, 0, 0);
        }
    }
  }

  // in-block reduce of the 2 k-slices (ks=1 -> ks=0), then write partial tile
  __syncthreads();
  float* red = (float*)lds;
  const int rbase = (wm * 64 + lane) * 68;
  if (ks == 1) {
#pragma unroll
    for (int j = 0; j < 16; ++j) {
      const int mf = j >> 3, nf = (j >> 2) & 1, r0 = (j & 3) * 4;
      float4 v;
      v.x = acc[mf][nf][r0 + 0]; v.y = acc[mf][nf][r0 + 1];
      v.z = acc[mf][nf][r0 + 2]; v.w = acc[mf][nf][r0 + 3];
      *(float4*)&red[rbase + j * 4] = v;
    }
  }
  __syncthreads();
  if (ks == 0) {
#pragma unroll
    for (int j = 0; j < 16; ++j) {
      const int mf = j >> 3, nf = (j >> 2) & 1, r0 = (j & 3) * 4;
      float4 v = *(const float4*)&red[rbase + j * 4];
      acc[mf][nf][r0 + 0] += v.x; acc[mf][nf][r0 + 1] += v.y;
      acc[mf][nf][r0 + 2] += v.z; acc[mf][nf][r0 + 3] += v.w;
    }
    float* Pk = P + (size_t)kb * 512 * N;
#pragma unroll
    for (int mf = 0; mf < 2; ++mf) {
      const int n = n0 + wm * 64 + (lane & 31);
#pragma unroll
      for (int nf = 0; nf < 2; ++nf)
#pragma unroll
        for (int r = 0; r < 16; ++r) {
          const int m = m0 + mf * 32 + (r & 3) + 8 * (r >> 2) + 4 * (lane >> 5);
          Pk[(size_t)m * N + n + nf * 32] = acc[mf][nf][r];
        }
    }
  }
}

// Fused: (P0+P1 -> xz) conv1d+SiLU -> x_proj -> dt_proj+softplus -> SSM -> gate -> y splits
__global__ __launch_bounds__(256) void k_fused(
    const float* __restrict__ pz0, const float* __restrict__ pz1,
    const float* __restrict__ cst, const float* __restrict__ sst,
    const float* __restrict__ cw, const float* __restrict__ cb,
    const float* __restrict__ xpw, const float* __restrict__ dtw, const float* __restrict__ dtb,
    const float* __restrict__ alog, const float* __restrict__ dpar,
    ushort_t* __restrict__ y0, ushort_t* __restrict__ y1, ushort_t* __restrict__ y2) {
  __shared__ float sxc[2][D_INNER];
  __shared__ float sxdb[2][96];
  const int t = threadIdx.x;
  const int b0 = blockIdx.x * 2;

#pragma unroll
  for (int bb = 0; bb < 2; ++bb) {
    const int b = b0 + bb;
    for (int d = t; d < D_INNER; d += 256) {
      float4 c = *(const float4*)&cst[((size_t)b * D_INNER + d) * 4];
      float4 w = *(const float4*)&cw[d * 4];
      const size_t xi = (size_t)b * 4096 + d;
      float xv = pz0[xi] + pz1[xi];
      float a = c.y * w.x + c.z * w.y + c.w * w.z + xv * w.w + cb[d];
      sxc[bb][d] = siluf_(a);
    }
  }
  __syncthreads();

  const int wave = t >> 6, lane = t & 63;
  for (int r = wave * 24; r < wave * 24 + 24; ++r) {
    float a0 = 0.f, a1 = 0.f;
    const float* wr = &xpw[(size_t)r * D_INNER];
    for (int k = lane; k < D_INNER; k += 64) {
      float wv = wr[k];
      a0 += wv * sxc[0][k];
      a1 += wv * sxc[1][k];
    }
    a0 = waveRedSum(a0);
    a1 = waveRedSum(a1);
    if (lane == 0) { sxdb[0][r] = a0; sxdb[1][r] = a1; }
  }
  __syncthreads();

  for (int d = t; d < D_INNER; d += 256) {
    float An[D_STATE];
#pragma unroll
    for (int n = 0; n < D_STATE; ++n) An[n] = -expf(alog[d * D_STATE + n]);
    float dtwv[DT_RANK];
#pragma unroll
    for (int j4 = 0; j4 < DT_RANK / 4; ++j4)
      *(float4*)&dtwv[j4 * 4] = *(const float4*)&dtw[(size_t)d * DT_RANK + j4 * 4];
    const float dtbv = dtb[d], dp = dpar[d];
#pragma unroll
    for (int bb = 0; bb < 2; ++bb) {
      const int b = b0 + bb;
      float dtr = dtbv;
#pragma unroll
      for (int j = 0; j < DT_RANK; ++j) dtr += sxdb[bb][j] * dtwv[j];
      float dtv = softplusf_(dtr);
      float xcv = sxc[bb][d];
      float dx = dtv * xcv;
      const float* srow = &sst[((size_t)b * D_INNER + d) * D_STATE];
      float acc = 0.f;
#pragma unroll
      for (int n = 0; n < D_STATE; ++n) {
        float Bn = sxdb[bb][DT_RANK + n];
        float Cn = sxdb[bb][DT_RANK + D_STATE + n];
        float sNew = srow[n] * expf(dtv * An[n]) + dx * Bn;
        acc += sNew * Cn;
      }
      float yv = acc + dp * xcv;
      const size_t zi = (size_t)b * 4096 + D_INNER + d;
      float zv = pz0[zi] + pz1[zi];
      yv *= siluf_(zv);
      ushort_t s0, s1, s2; split3(yv, s0, s1, s2);
      const size_t off = (size_t)b * D_INNER + d;
      y0[off] = s0; y1[off] = s1; y2[off] = s2;
    }
  }
}

// h = sum of 8 out_proj partials; also emit h bf16 3-splits for next layer's GEMM
__global__ __launch_bounds__(256) void k_reduce_out(const float* __restrict__ P,
    float* __restrict__ h, ushort_t* __restrict__ h0, ushort_t* __restrict__ h1,
    ushort_t* __restrict__ h2) {
  const int i = blockIdx.x * 256 + threadIdx.x;  // float4 index, n4 = 131072
  float4 a = ((const float4*)P)[i];
#pragma unroll
  for (int p = 1; p < 8; ++p) {
    float4 b = ((const float4*)P)[(size_t)p * 131072 + i];
    a.x += b.x; a.y += b.y; a.z += b.z; a.w += b.w;
  }
  ((float4*)h)[i] = a;
  float fv[4] = {a.x, a.y, a.z, a.w};
  ushort_t u0[4], u1[4], u2[4];
#pragma unroll
  for (int j = 0; j < 4; ++j) split3(fv[j], u0[j], u1[j], u2[j]);
  ((uint2*)h0)[i] = make_uint2((uint_t)u0[0] | ((uint_t)u0[1] << 16), (uint_t)u0[2] | ((uint_t)u0[3] << 16));
  ((uint2*)h1)[i] = make_uint2((uint_t)u1[0] | ((uint_t)u1[1] << 16), (uint_t)u1[2] | ((uint_t)u1[3] << 16));
  ((uint2*)h2)[i] = make_uint2((uint_t)u2[0] | ((uint_t)u2[1] << 16), (uint_t)u2[2] | ((uint_t)u2[3] << 16));
}

__global__ __launch_bounds__(256) void k_layernorm(const float* __restrict__ h,
    const float* __restrict__ lnw, const float* __restrict__ lnb, float* __restrict__ out) {
  __shared__ float red[4];
  const int b = blockIdx.x, t = threadIdx.x;
  const float* row = h + (size_t)b * D_MODEL;
  float4 x = *(const float4*)&row[t * 4];
  float s = x.x + x.y + x.z + x.w;
  s = waveRedSum(s);
  const int wave = t >> 6, lane = t & 63;
  if (lane == 0) red[wave] = s;
  __syncthreads();
  float mu = (red[0] + red[1] + red[2] + red[3]) * (1.f / 1024.f);
  float d0 = x.x - mu, d1 = x.y - mu, d2 = x.z - mu, d3 = x.w - mu;
  float q = d0 * d0 + d1 * d1 + d2 * d2 + d3 * d3;
  q = waveRedSum(q);
  __syncthreads();
  if (lane == 0) red[wave] = q;
  __syncthreads();
  float var = (red[0] + red[1] + red[2] + red[3]) * (1.f / 1024.f);
  float inv = 1.f / sqrtf(var + 1e-5f);
  float4 wv = *(const float4*)&lnw[t * 4];
  float4 bv = *(const float4*)&lnb[t * 4];
  float4 o;
  o.x = d0 * inv * wv.x + bv.x;
  o.y = d1 * inv * wv.y + bv.y;
  o.z = d2 * inv * wv.z + bv.z;
  o.w = d3 * inv * wv.w + bv.w;
  *(float4*)&out[(size_t)b * D_MODEL + t * 4] = o;
}

extern "C" void kernel_launch(void* const* d_in, const int* in_sizes, int n_in,
                              void* d_out, int out_size, void* d_ws, size_t ws_size,
                              hipStream_t stream) {
  const float* x_t  = (const float*)d_in[0];
  const float* cst  = (const float*)d_in[1];
  const float* sst  = (const float*)d_in[2];
  const float* Win  = (const float*)d_in[3];
  const float* bin  = (const float*)d_in[4];
  const float* ipw  = (const float*)d_in[5];
  const float* cw   = (const float*)d_in[6];
  const float* cb   = (const float*)d_in[7];
  const float* xpw  = (const float*)d_in[8];
  const float* dtw  = (const float*)d_in[9];
  const float* dtb  = (const float*)d_in[10];
  const float* alog = (const float*)d_in[11];
  const float* dpar = (const float*)d_in[12];
  const float* opw  = (const float*)d_in[13];
  const float* lnw  = (const float*)d_in[14];
  const float* lnb  = (const float*)d_in[15];

  float* ws  = (float*)d_ws;
  float* h   = ws;                         // 524288 f32
  float* Pin = h + 524288;                 // 2 x 2097152 f32
  float* Pout = Pin + 4194304;             // 8 x 524288 f32
  ushort_t* u = (ushort_t*)(Pout + 4194304);
  ushort_t* h0 = u;              ushort_t* h1 = h0 + 524288;   ushort_t* h2 = h1 + 524288;
  ushort_t* y0 = h2 + 524288;    ushort_t* y1 = y0 + 1048576;  ushort_t* y2 = y1 + 1048576;
  ushort_t* iw0 = y2 + 1048576;
  ushort_t* iw1 = iw0 + 50331648;
  ushort_t* iw2 = iw1 + 50331648;
  ushort_t* ow0 = iw2 + 50331648;
  ushort_t* ow1 = ow0 + 25165824;
  ushort_t* ow2 = ow1 + 25165824;

  k_presplit<<<2048, 256, 0, stream>>>(ipw, iw0, iw1, iw2, 6291456);
  k_presplit<<<2048, 256, 0, stream>>>(opw, ow0, ow1, ow2, 3145728);
  k_input_proj<<<2048, 256, 0, stream>>>(x_t, Win, bin, h0, h1, h2);

  for (int l = 0; l < DEPTH; ++l) {
    const size_t iwo = (size_t)l * 4096 * 1024;
    const size_t owo = (size_t)l * 1024 * 2048;
    // in_proj: P_in[2][512][4096], M=512 K=1024, MBLK=8 NBLK=32 KSPLIT=2 KLEN=512
    k_gemm6<8, 32, 2, 512><<<512, 256, 0, stream>>>(
        h0, h1, h2, iw0 + iwo, iw1 + iwo, iw2 + iwo, Pin, 4096, 1024);
    k_fused<<<256, 256, 0, stream>>>(
        Pin, Pin + 2097152,
        cst + (size_t)l * BATCH * D_INNER * D_CONV,
        sst + (size_t)l * BATCH * D_INNER * D_STATE,
        cw + (size_t)l * D_INNER * D_CONV, cb + (size_t)l * D_INNER,
        xpw + (size_t)l * 96 * D_INNER,
        dtw + (size_t)l * D_INNER * DT_RANK, dtb + (size_t)l * D_INNER,
        alog + (size_t)l * D_INNER * D_STATE, dpar + (size_t)l * D_INNER,
        y0, y1, y2);
    // out_proj: P_out[8][512][1024], M=512 K=2048, MBLK=8 NBLK=8 KSPLIT=8 KLEN=256
    k_gemm6<8, 8, 8, 256><<<512, 256, 0, stream>>>(
        y0, y1, y2, ow0 + owo, ow1 + owo, ow2 + owo, Pout, 1024, 2048);
    k_reduce_out<<<512, 256, 0, stream>>>(Pout, h, h0, h1, h2);
  }

  k_layernorm<<<512, 256, 0, stream>>>(h, lnw, lnb, (float*)d_out);
}